// Round 1
// baseline (381.443 us; speedup 1.0000x reference)
//
#include <hip/hip_runtime.h>
#include <cstdint>
#include <cstddef>

// NMS face detector head.
// Input: det (N x 17) fp32. Output: 5 x 17 fp32.
// Pipeline (all on `stream`, graph-capture safe):
//   memset keys -> prep(+argmax round 0) -> 4x fused suppress+argmax -> gather.
//
// Key encoding for argmax with numpy first-index tie-break:
//   key = (float_bits(score) << 32) | (0xFFFFFFFF - idx),  score in {0} U [0.5, 1)
//   score==0 is the "-inf / suppressed / below-threshold" sentinel (valid scores >= 0.5).

typedef unsigned long long ull;

#define NMS_ROUNDS 5
#define SCORE_THR 0.5f
#define IOU_THR 0.3f
#define CLIP_MAX 1.0e8f
#define IMG_SIZE 128.0f
#define NCOL 17

__device__ __forceinline__ ull pack_key(float s, unsigned idx) {
    return ((ull)__float_as_uint(s) << 32) | (ull)(0xFFFFFFFFu - idx);
}

// Block (256 threads) max-reduce of keys; result valid on thread 0.
__device__ __forceinline__ ull block_max_key(ull key) {
    #pragma unroll
    for (int off = 32; off > 0; off >>= 1) {
        ull o = __shfl_down(key, off, 64);
        if (o > key) key = o;
    }
    __shared__ ull wmax[4];
    int wid = threadIdx.x >> 6;
    if ((threadIdx.x & 63) == 0) wmax[wid] = key;
    __syncthreads();
    if (threadIdx.x == 0) {
        key = wmax[0];
        #pragma unroll
        for (int w = 1; w < 4; ++w) if (wmax[w] > key) key = wmax[w];
    }
    return key;
}

// One block handles 256 rows. Coalesced load of the 256x17 tile into LDS,
// then per-row box/score computation + round-0 argmax contribution.
__global__ __launch_bounds__(256) void prep_kernel(const float* __restrict__ det,
                                                   float4* __restrict__ boxes,
                                                   float* __restrict__ scores,
                                                   ull* __restrict__ keys,
                                                   int N) {
    __shared__ float tile[256 * NCOL];
    const int t = threadIdx.x;
    const int base = blockIdx.x * 256;
    const long f0 = (long)base * NCOL;
    const long total = (long)N * NCOL;
    #pragma unroll
    for (int k = 0; k < NCOL; ++k) {
        long f = f0 + (long)k * 256 + t;
        if (f < total) tile[k * 256 + t] = det[f];
    }
    __syncthreads();

    ull key = 0;
    const int r = base + t;
    if (r < N) {
        // row layout: [cy, cx, sh, sw, ..., score]
        float cy = tile[t * NCOL + 0];
        float cx = tile[t * NCOL + 1];
        float sh = tile[t * NCOL + 2];
        float sw = tile[t * NCOL + 3];
        float sc = tile[t * NCOL + 16];
        // tl = clip(c - s*0.5, 0, 1e8); br = c + s*0.5  (x = col 1, y = col 0)
        float x1 = fminf(fmaxf(cx - sw * 0.5f, 0.0f), CLIP_MAX);
        float y1 = fminf(fmaxf(cy - sh * 0.5f, 0.0f), CLIP_MAX);
        float x2 = cx + sw * 0.5f;
        float y2 = cy + sh * 0.5f;
        float s = (sc >= SCORE_THR) ? sc : 0.0f;
        boxes[r] = make_float4(x1, y1, x2, y2);
        scores[r] = s;
        if (s > 0.0f) key = pack_key(s, (unsigned)r);
    }

    key = block_max_key(key);
    if (threadIdx.x == 0 && key != 0) atomicMax(&keys[0], key);
}

// Round k (k = 1..4): suppress vs. winner of round k-1, then argmax -> keys[k].
__global__ __launch_bounds__(256) void round_kernel(const float4* __restrict__ boxes,
                                                    float* __restrict__ scores,
                                                    ull* __restrict__ keys,
                                                    int N, int k) {
    __shared__ float4 selb;
    __shared__ float sela;
    __shared__ int valid;
    if (threadIdx.x == 0) {
        ull pk = keys[k - 1];
        unsigned sb = (unsigned)(pk >> 32);
        if (sb != 0u) {
            unsigned idx = 0xFFFFFFFFu - (unsigned)(pk & 0xFFFFFFFFull);
            float4 b = boxes[idx];
            selb = b;
            sela = (b.z - b.x) * (b.w - b.y);   // same op order as reference areas
            valid = 1;
        } else {
            valid = 0;
        }
    }
    __syncthreads();

    ull key = 0;
    const int stride = gridDim.x * 256;
    for (int i = blockIdx.x * 256 + threadIdx.x; i < N; i += stride) {
        float s = scores[i];
        if (s > 0.0f) {
            if (valid) {
                float4 b = boxes[i];
                float iw = fmaxf(fminf(b.z, selb.z) - fmaxf(b.x, selb.x), 0.0f);
                float ih = fmaxf(fminf(b.w, selb.w) - fmaxf(b.y, selb.y), 0.0f);
                float inter = iw * ih;
                float area = (b.z - b.x) * (b.w - b.y);
                float iou = inter / (area + sela - inter + 1e-9f);
                if (iou > IOU_THR) { s = 0.0f; scores[i] = 0.0f; }
            }
            if (s > 0.0f) {
                ull nk = pack_key(s, (unsigned)i);
                if (nk > key) key = nk;
            }
        }
    }

    key = block_max_key(key);
    if (threadIdx.x == 0 && key != 0) atomicMax(&keys[k], key);
}

// Decode the 5 winners, write 5x17 output (cols 0..15 scaled by 128).
__global__ void gather_kernel(const float* __restrict__ det,
                              const ull* __restrict__ keys,
                              float* __restrict__ out) {
    int t = threadIdx.x;
    if (t < NMS_ROUNDS * NCOL) {
        int i = t / NCOL;
        int j = t - i * NCOL;
        ull k = keys[i];
        unsigned sb = (unsigned)(k >> 32);
        float v = 0.0f;
        if (sb != 0u) {
            unsigned idx = 0xFFFFFFFFu - (unsigned)(k & 0xFFFFFFFFull);
            v = det[(size_t)idx * NCOL + j];
            if (j < 16) v *= IMG_SIZE;
        }
        out[t] = v;
    }
}

extern "C" void kernel_launch(void* const* d_in, const int* in_sizes, int n_in,
                              void* d_out, int out_size, void* d_ws, size_t ws_size,
                              hipStream_t stream) {
    const float* det = (const float*)d_in[0];
    float* out = (float*)d_out;
    const int N = in_sizes[0] / NCOL;   // 2,000,000

    // Workspace layout: [ boxes: 16*N | scores: 4*N | keys: 5*8 ]  (~40 MB)
    char* ws = (char*)d_ws;
    float4* boxes = (float4*)ws;
    float*  scores = (float*)(ws + (size_t)16 * N);
    ull*    keys   = (ull*)(ws + (size_t)20 * N);   // 20*N divisible by 8

    hipMemsetAsync(keys, 0, NMS_ROUNDS * sizeof(ull), stream);

    int nb = (N + 255) / 256;
    prep_kernel<<<nb, 256, 0, stream>>>(det, boxes, scores, keys, N);
    for (int k = 1; k < NMS_ROUNDS; ++k)
        round_kernel<<<2048, 256, 0, stream>>>(boxes, scores, keys, N, k);
    gather_kernel<<<1, 128, 0, stream>>>(det, keys, out);
}